// Round 5
// baseline (134.241 us; speedup 1.0000x reference)
//
#include <hip/hip_runtime.h>

// b=16, n=m=2048, d=dv=128, fp32 in/out, temp=sqrt(128).
// Prep: K -> bf16 scaled by log2e/temp; V -> Vt[b][dv][m] bf16. Q cast in-kernel.
// Attention: swapped S^T = K.Q^T via 32x32x16 bf16 MFMA, P = exp2(S),
// P->A-frag via v_cvt_pk_bf16_f32 + v_permlane32_swap_b32, PV accumulate.
// K/V staged by global_load_lds.
// Round-5: TRIPLE-buffered K (2-tile prefetch depth), double-buffered V.
//   bar1: vmcnt(8) [K(t) landed; issued 2 bodies ago -> ~2 tiles slack] + s_barrier
//   QK(t) ; STAGE_K(t+2) ; STAGE_V(t+1) ; softmax(t)
//   bar2: vmcnt(8) [V(t) landed; ~1.3 tiles slack] + s_barrier
//   PV(t)
// Issue order [K(t+2); V(t+1)] makes "newer than K(t)" = "newer than V(t)" = 8
// -> uniform vmcnt(8) at both barriers; bar1's wait is usually pre-satisfied.
// Round-4's bar1 vmcnt(4) waited on K issued only ~0.5 tile earlier (< L3/HBM
// latency) -> per-tile stall; this removes it. LDS 80KB/block = 2 blocks/CU
// (full 160KB pool). Wrap-staging keeps counts uniform; epilogue __syncthreads
// drains. Buffer-overwrite safety: a wave staging kbuf[(t+2)%3] passed bar1(t)
// => all waves finished QK(t-1) (the last reader of that buffer).
// Block = 4 waves: 2 q-waves (BQ=64) x 2 m-waves (BK=64 split 32/32).
// Grid 16x32 = 512 blocks -> 2 blocks/CU, 8 waves/CU.

#define BATCH 16
#define SEQ   2048
#define DIM   128
#define NT    (SEQ / 64)

typedef short bf16x8 __attribute__((ext_vector_type(8)));
typedef float f32x16 __attribute__((ext_vector_type(16)));

static __device__ __forceinline__ unsigned pk2(float lo, float hi) {
  union { float f; unsigned u; } a, b;
  a.f = lo; b.f = hi;
  return ((b.u + 0x8000u) & 0xffff0000u) | ((a.u + 0x8000u) >> 16);
}
static __device__ __forceinline__ float fast_exp2(float x) {
#if __has_builtin(__builtin_amdgcn_exp2f)
  return __builtin_amdgcn_exp2f(x);
#else
  return exp2f(x);
#endif
}

typedef __attribute__((address_space(1))) const unsigned int g_u32;
typedef __attribute__((address_space(3))) unsigned int l_u32;
static __device__ __forceinline__ void gl2lds16(const unsigned short* g, unsigned short* l) {
  // per-lane global src; wave-uniform LDS base, HW writes base + lane*16
  __builtin_amdgcn_global_load_lds((g_u32*)g, (l_u32*)l, 16, 0, 0);
}

// ---- fused preprocess: blocks [0,2048): K cvt+scale; [2048,3072): V transpose ----
__global__ __launch_bounds__(256)
void prep_kernel(const float* __restrict__ K, const float* __restrict__ V,
                 unsigned short* __restrict__ Kb, unsigned short* __restrict__ Vt,
                 float scale) {
  const int bx = blockIdx.x, tid = threadIdx.x;
  if (bx < 2048) {
    size_t idx = (size_t)bx * 256 + tid;
    const float4* kf = (const float4*)K;
    float4 a = kf[idx * 2], c = kf[idx * 2 + 1];
    uint4 o;
    o.x = pk2(a.x * scale, a.y * scale);
    o.y = pk2(a.z * scale, a.w * scale);
    o.z = pk2(c.x * scale, c.y * scale);
    o.w = pk2(c.z * scale, c.w * scale);
    ((uint4*)Kb)[idx] = o;
  } else {
    __shared__ float tile[128][33];
    const int vb = bx - 2048;                 // 1024 blocks
    const int b = vb >> 6, r = vb & 63;
    const int m0 = (r & 15) * 128, d0 = (r >> 4) * 32;
    const int c = tid & 7, mr = tid >> 3;
    const float* src = V + ((size_t)(b * SEQ) + m0) * DIM + d0;
#pragma unroll
    for (int it = 0; it < 4; ++it) {
      int m = it * 32 + mr;
      float4 x = *(const float4*)(src + (size_t)m * DIM + c * 4);
      tile[m][c * 4 + 0] = x.x; tile[m][c * 4 + 1] = x.y;
      tile[m][c * 4 + 2] = x.z; tile[m][c * 4 + 3] = x.w;
    }
    __syncthreads();
    const int dr = tid >> 3, s = tid & 7;
    unsigned short* dst = Vt + ((size_t)(b * DIM) + d0 + dr) * SEQ + m0;
#pragma unroll
    for (int it = 0; it < 2; ++it) {
      int slot = it * 8 + s;
      uint4 o;
      o.x = pk2(tile[slot * 8 + 0][dr], tile[slot * 8 + 1][dr]);
      o.y = pk2(tile[slot * 8 + 2][dr], tile[slot * 8 + 3][dr]);
      o.z = pk2(tile[slot * 8 + 4][dr], tile[slot * 8 + 5][dr]);
      o.w = pk2(tile[slot * 8 + 6][dr], tile[slot * 8 + 7][dr]);
      *(uint4*)(dst + slot * 8) = o;
    }
  }
}

// ---- main flash attention ----
// LDS (bytes): K bufs @0, @16384, @32768 (3x16KB); V bufs @49152, @65536 (2x16KB)
// total 81920 B. K buf: 64 rows x 256B linear, [row][x] holds
// K[m0+row][x ^ ((row&15)<<4)]. V buf: 128 rows x 128B linear, [row][x] holds
// Vt[row][m0 + (x ^ ((row&7)<<4))/2].
// Epilogue (after __syncthreads) aliases: cb f32[2][4096] @0, cbL @32768.

__global__ __launch_bounds__(256, 2)
void attn_kernel(const float* __restrict__ Qf,
                 const unsigned short* __restrict__ Kb,
                 const unsigned short* __restrict__ Vtb,
                 float* __restrict__ out) {
  __shared__ __align__(1024) unsigned char smem[81920];
  unsigned short* sm16 = (unsigned short*)smem;

  const int tid  = threadIdx.x;
  const int wv   = tid >> 6;
  const int w_q  = wv & 1;                  // q-subtile (32 rows)
  const int w_m  = wv >> 1;                 // m-half (32 cols) of the 64-tile
  const int lane = tid & 63;
  const int l31  = lane & 31;
  const int q2   = lane >> 5;
  const int b    = blockIdx.x;
  const int q0   = blockIdx.y * 64 + w_q * 32;

  const unsigned short* kb = Kb  + (size_t)b * SEQ * DIM;   // [m][d], pre-scaled
  const unsigned short* vb = Vtb + (size_t)b * SEQ * DIM;   // [dv][m]

  // Q fragments (B-operand of swapped QK^T): lane (l31,q2) holds Q[q0+l31][c*16+q2*8+j]
  bf16x8 aq[8];
  {
    const float* qp = Qf + ((size_t)(b * SEQ) + q0 + l31) * DIM + q2 * 8;
#pragma unroll
    for (int c = 0; c < 8; ++c) {
      float4 x = *(const float4*)(qp + c * 16);
      float4 y = *(const float4*)(qp + c * 16 + 4);
      union { unsigned i[4]; bf16x8 v; } u;
      u.i[0] = pk2(x.x, x.y); u.i[1] = pk2(x.z, x.w);
      u.i[2] = pk2(y.x, y.y); u.i[3] = pk2(y.z, y.w);
      aq[c] = u.v;
    }
  }

  // staging source offsets (ushort units); LDS dest linear, global src pre-swizzled
  unsigned kgo[4], vgo[4];
#pragma unroll
  for (int i = 0; i < 4; ++i) {
    int ch = wv * 4 + i;
    int krow = ch * 4 + (lane >> 4);
    kgo[i] = (unsigned)(krow * 128) + ((((lane & 15) << 4) ^ ((krow & 15) << 4)) >> 1);
    int vrow = ch * 8 + (lane >> 3);
    vgo[i] = (unsigned)(vrow * 2048) + ((((lane & 7) << 4) ^ ((vrow & 7) << 4)) >> 1);
  }

  // swizzled read base offsets (bytes, within a buffer)
  const int kro = ((w_m * 32 + l31) << 8) + ((q2 << 4) ^ ((l31 & 15) << 4));
  const int vro = (l31 << 7) + (((w_m << 6) + (q2 << 4)) ^ ((l31 & 7) << 4));

  f32x16 oacc[4];
#pragma unroll
  for (int t = 0; t < 4; ++t)
#pragma unroll
    for (int i = 0; i < 16; ++i) oacc[t][i] = 0.0f;
  float ls[4] = {0.0f, 0.0f, 0.0f, 0.0f};

#define STAGE_K(TK, KOFF) do {                                               \
    const unsigned short* kt_b = kb + ((size_t)(TK) << 13);                  \
    unsigned short* kd = sm16 + (((KOFF) + wv * 4096) >> 1);                 \
    _Pragma("unroll")                                                        \
    for (int i = 0; i < 4; ++i) gl2lds16(kt_b + kgo[i], kd + i * 512);       \
  } while (0)
#define STAGE_V(TV, VOFF) do {                                               \
    const unsigned short* vt_b = vb + ((TV) << 6);                           \
    unsigned short* vd = sm16 + (((VOFF) + wv * 4096) >> 1);                 \
    _Pragma("unroll")                                                        \
    for (int i = 0; i < 4; ++i) gl2lds16(vt_b + vgo[i], vd + i * 512);       \
  } while (0)

  // prologue: K(0), V(0), K(1)  (12 loads in flight)
  STAGE_K(0, 0);
  STAGE_V(0, 49152);
  STAGE_K(1, 16384);

  int kcur = 0;        // K buf offset of tile t     (0 / 16384 / 32768)
  int kstg = 32768;    // K buf offset for tile t+2
  int vcur = 0;        // V buf sub-offset of tile t (0 / 16384), base 49152

  for (int kt = 0; kt < NT; ++kt) {
    // ---- bar1: K(t) landed for ALL waves (newer-than-K(t) = 8 loads) ----
    asm volatile("s_waitcnt vmcnt(8)" ::: "memory");
    __builtin_amdgcn_s_barrier();
    __builtin_amdgcn_sched_barrier(0);

    const unsigned char* kB = smem + kcur;
    const unsigned char* vB = smem + 49152 + vcur;

    // S^T = K . Q^T : two independent 4-deep MFMA chains, merged at the end.
    // lane (l31,q2) holds S[q=l31][m=(r&3)+8*(r>>2)+4*q2]
    f32x16 se, so;
#pragma unroll
    for (int i = 0; i < 16; ++i) { se[i] = 0.0f; so[i] = 0.0f; }
    __builtin_amdgcn_s_setprio(1);
#pragma unroll
    for (int c = 0; c < 4; ++c) {
      bf16x8 b0 = *(const bf16x8*)(kB + (kro ^ ((2 * c) << 5)));
      se = __builtin_amdgcn_mfma_f32_32x32x16_bf16(b0, aq[2 * c], se, 0, 0, 0);
      bf16x8 b1 = *(const bf16x8*)(kB + (kro ^ ((2 * c + 1) << 5)));
      so = __builtin_amdgcn_mfma_f32_32x32x16_bf16(b1, aq[2 * c + 1], so, 0, 0, 0);
    }
    __builtin_amdgcn_s_setprio(0);
    __builtin_amdgcn_sched_barrier(0);

    // prefetch: K two tiles ahead, V one tile ahead. Wrap indices (&31) keep
    // per-wave vmcnt counts uniform; epilogue __syncthreads drains the wrap.
    STAGE_K((kt + 2) & (NT - 1), kstg);
    STAGE_V((kt + 1) & (NT - 1), 49152 + (vcur ^ 16384));
    __builtin_amdgcn_sched_barrier(0);

    // P = exp2(S); partial row sums in 4 independent accumulators
    float p[16];
#pragma unroll
    for (int i = 0; i < 16; ++i) p[i] = fast_exp2(se[i] + so[i]);
#pragma unroll
    for (int i = 0; i < 4; ++i) {
      ls[0] += p[4 * i + 0]; ls[1] += p[4 * i + 1];
      ls[2] += p[4 * i + 2]; ls[3] += p[4 * i + 3];
    }

    // P -> PV A-fragments fully in-register: cvt_pk pairs + permlane32_swap
    unsigned d0, d1, d2, d3, d4, d5, d6, d7;
    asm("v_cvt_pk_bf16_f32 %0, %1, %2" : "=v"(d0) : "v"(p[0]),  "v"(p[1]));
    asm("v_cvt_pk_bf16_f32 %0, %1, %2" : "=v"(d1) : "v"(p[2]),  "v"(p[3]));
    asm("v_cvt_pk_bf16_f32 %0, %1, %2" : "=v"(d2) : "v"(p[4]),  "v"(p[5]));
    asm("v_cvt_pk_bf16_f32 %0, %1, %2" : "=v"(d3) : "v"(p[6]),  "v"(p[7]));
    asm("v_cvt_pk_bf16_f32 %0, %1, %2" : "=v"(d4) : "v"(p[8]),  "v"(p[9]));
    asm("v_cvt_pk_bf16_f32 %0, %1, %2" : "=v"(d5) : "v"(p[10]), "v"(p[11]));
    asm("v_cvt_pk_bf16_f32 %0, %1, %2" : "=v"(d6) : "v"(p[12]), "v"(p[13]));
    asm("v_cvt_pk_bf16_f32 %0, %1, %2" : "=v"(d7) : "v"(p[14]), "v"(p[15]));
    asm("v_permlane32_swap_b32 %0, %1" : "+v"(d0), "+v"(d2));
    asm("v_permlane32_swap_b32 %0, %1" : "+v"(d1), "+v"(d3));
    asm("v_permlane32_swap_b32 %0, %1" : "+v"(d4), "+v"(d6));
    asm("v_permlane32_swap_b32 %0, %1" : "+v"(d5), "+v"(d7));
    union { unsigned u[4]; bf16x8 v; } pu0, pu1;
    pu0.u[0] = d0; pu0.u[1] = d1; pu0.u[2] = d2; pu0.u[3] = d3;
    pu1.u[0] = d4; pu1.u[1] = d5; pu1.u[2] = d6; pu1.u[3] = d7;

    // ---- bar2: V(t) landed for ALL waves (newer-than-V(t) = 8 loads) ----
    asm volatile("s_waitcnt vmcnt(8)" ::: "memory");
    __builtin_amdgcn_s_barrier();
    __builtin_amdgcn_sched_barrier(0);

    // O += P . V  over this wave's m-half
    __builtin_amdgcn_s_setprio(1);
#pragma unroll
    for (int t = 0; t < 4; ++t) {
      bf16x8 bv0 = *(const bf16x8*)(vB + t * 4096 + vro);
      oacc[t] = __builtin_amdgcn_mfma_f32_32x32x16_bf16(pu0.v, bv0, oacc[t], 0, 0, 0);
      bf16x8 bv1 = *(const bf16x8*)(vB + t * 4096 + (vro ^ 32));
      oacc[t] = __builtin_amdgcn_mfma_f32_32x32x16_bf16(pu1.v, bv1, oacc[t], 0, 0, 0);
    }
    __builtin_amdgcn_s_setprio(0);
    __builtin_amdgcn_sched_barrier(0);

    // rotate buffers
    kcur = (kcur == 32768) ? 0 : kcur + 16384;
    kstg = (kstg == 32768) ? 0 : kstg + 16384;
    vcur ^= 16384;
  }
#undef STAGE_K
#undef STAGE_V

  float lsum = (ls[0] + ls[1]) + (ls[2] + ls[3]);
  // merge q2 halves of the row sum: lane (l31,*) -> sum over this wave's 32 m
  lsum += __shfl_xor(lsum, 32, 64);

  // combine the two m-halves through LDS, normalize, coalesced store
  __syncthreads();                          // drains wrap-stage; all tile reads done
  float* cb  = (float*)smem;                // [2][64][64] partials = 32768 B
  float* cbL = (float*)(smem + 32768);      // [2][64] row sums
  if (w_m == 1) {
    float* my = cb + w_q * 4096;
#pragma unroll
    for (int t = 0; t < 4; ++t)
#pragma unroll
      for (int r = 0; r < 16; ++r)
        my[(t * 16 + r) * 64 + lane] = oacc[t][r];
  }
  cbL[w_m * 64 + w_q * 32 + l31] = lsum;    // both q2 lanes write same value
  __syncthreads();
  if (w_m == 0) {
    const float* pr = cb + w_q * 4096;
    float linv[16];
#pragma unroll
    for (int r = 0; r < 16; ++r) {
      int qr = (r & 3) + ((r >> 2) << 3) + (q2 << 2);
      linv[r] = 1.0f / (cbL[w_q * 32 + qr] + cbL[64 + w_q * 32 + qr]);
    }
    float* ob = out + ((size_t)(b * SEQ) + q0) * DIM;
#pragma unroll
    for (int t = 0; t < 4; ++t)
#pragma unroll
      for (int r = 0; r < 16; ++r) {
        int qr = (r & 3) + ((r >> 2) << 3) + (q2 << 2);
        ob[(size_t)qr * DIM + t * 32 + l31] = (oacc[t][r] + pr[(t * 16 + r) * 64 + lane]) * linv[r];
      }
  }
}

extern "C" void kernel_launch(void* const* d_in, const int* in_sizes, int n_in,
                              void* d_out, int out_size, void* d_ws, size_t ws_size,
                              hipStream_t stream) {
  const float* Q = (const float*)d_in[0];
  const float* K = (const float*)d_in[1];
  const float* V = (const float*)d_in[2];
  float* out = (float*)d_out;

  const size_t elems = (size_t)BATCH * SEQ * DIM;   // 4,194,304
  unsigned short* Kb = (unsigned short*)d_ws;       // 8 MB
  unsigned short* Vt = Kb + elems;                  // 8 MB (ws >= 16 MB)

  const double TEMPERATURE = 11.313708498984761;
  const float scale = (float)(1.4426950408889634 / TEMPERATURE);  // log2(e)/temp on K

  prep_kernel<<<3072, 256, 0, stream>>>(K, V, Kb, Vt, scale);
  attn_kernel<<<dim3(BATCH, SEQ / 64), 256, 0, stream>>>(Q, Kb, Vt, out);
}